// Round 15
// baseline (1502.195 us; speedup 1.0000x reference)
//
#include <hip/hip_runtime.h>
#include <hip/hip_bf16.h>
#include <stdint.h>

// Swin windowed MHA: N=32, H=W=64, C=512, heads=16, head_dim=32, window 8x8 (E=64).
// conv x->bf16 ; pack qkv_w (fragment order) ; transpose out_w ; prep BM2 = bias+mask
// fused table (parked in d_out) ; k_winfuse (fused QKV-proj + windowed attn, 4 blocks/CU) ;
// GEMM2 (r12 structure, fp32 out).

typedef __attribute__((ext_vector_type(4))) float  f32x4;
typedef __attribute__((ext_vector_type(4))) float  fvec4;
typedef __attribute__((ext_vector_type(8))) short  s16x8;
typedef __attribute__((ext_vector_type(8))) __bf16 bf16x8;
typedef __attribute__((ext_vector_type(2))) unsigned int u32x2;
typedef __attribute__((ext_vector_type(4))) unsigned int u32x4;
typedef unsigned short u16;
typedef unsigned int   u32;
typedef __attribute__((ext_vector_type(4))) u16 u16x4;
typedef __attribute__((ext_vector_type(8))) u16 u16x8;

__device__ __forceinline__ u16 f2bf(float f) {
  u32 u = __builtin_bit_cast(u32, f);
  u32 r = (u + 0x7FFFu + ((u >> 16) & 1u)) >> 16;
  return (u16)r;
}
__device__ __forceinline__ u32 pk2(float x, float y) {
  return (u32)f2bf(x) | ((u32)f2bf(y) << 16);
}

__device__ __forceinline__ f32x4 mfma16(s16x8 a, s16x8 b, f32x4 c) {
  return __builtin_amdgcn_mfma_f32_16x16x32_bf16((bf16x8)a, (bf16x8)b, c, 0, 0, 0);
}

__device__ __forceinline__ void gload16(const u16* g, u16* l) {
  __builtin_amdgcn_global_load_lds(
      (const __attribute__((address_space(1))) u32*)g,
      (__attribute__((address_space(3))) u32*)l, 16, 0, 0);
}

#define BARRIER() asm volatile("s_barrier" ::: "memory")
#define WAITVM(n) asm volatile("s_waitcnt vmcnt(" #n ")" ::: "memory")

// ---------------- conversion / packing kernels ----------------
__global__ void k_conv_x(const float* __restrict__ x, u16* __restrict__ xb, int n8) {
  int i = blockIdx.x * 256 + threadIdx.x;
  if (i >= n8) return;
  fvec4 v0 = ((const fvec4*)x)[i * 2];
  fvec4 v1 = ((const fvec4*)x)[i * 2 + 1];
  u16x8 o;
  o[0] = f2bf(v0.x); o[1] = f2bf(v0.y); o[2] = f2bf(v0.z); o[3] = f2bf(v0.w);
  o[4] = f2bf(v1.x); o[5] = f2bf(v1.y); o[6] = f2bf(v1.z); o[7] = f2bf(v1.w);
  ((u16x8*)xb)[i] = o;
}

__global__ void k_transpose_w(const float* __restrict__ w, u16* __restrict__ wt, int K, int N) {
  int i = blockIdx.x * 256 + threadIdx.x;
  if (i >= K * N) return;
  int k = i / N, n = i - k * N;
  wt[n * K + k] = f2bf(w[i]);
}

// pack qkv_w [512][1536] f32 -> PW bf16 fragment order (r6-validated)
__global__ void k_pack_wqkv(const float* __restrict__ w, u16* __restrict__ pw) {
  int id = blockIdx.x * 256 + threadIdx.x;
  const int lane = id & 63;
  int r = id >> 6;
  const int kt = r & 15; r >>= 4;
  const int nf = r & 1;  r >>= 1;
  const int s = r % 3;
  const int H = r / 3;
  const int n = s * 512 + H * 32 + nf * 16 + (lane & 15);
  const int k0 = kt * 32 + (lane >> 4) * 8;
  u16 tmp[8];
#pragma unroll
  for (int j = 0; j < 8; ++j) tmp[j] = f2bf(w[(size_t)(k0 + j) * 1536 + n]);
  *(s16x8*)&pw[(size_t)id * 8] = *(const s16x8*)tmp;
}

// BM2[wh][ww][head][row][col] = rel_bias[head][row][col] + mask[wh][ww][row][col]
__global__ void k_prep_bm(const float* __restrict__ mask, const float* __restrict__ btab,
                          float* __restrict__ bm2) {
  int id = blockIdx.x * 256 + threadIdx.x;   // 4,194,304 total
  const int col = id & 63;
  const int row = (id >> 6) & 63;
  const int head = (id >> 12) & 15;
  const int wb = id >> 16;                   // wh*8+ww
  const int dh = (row >> 3) - (col >> 3) + 7;
  const int dw = (row & 7) - (col & 7) + 7;
  bm2[id] = btab[(dh * 15 + dw) * 16 + head] + mask[(size_t)(wb * 64 + row) * 64 + col];
}

// ---------------- fused QKV-proj + windowed attention ----------------
// Block = (window, head-quad): 8192 blocks, 256 thr = 4 waves, wave wid owns head hq*4+wid.
// Proj: M=64, per-wave N=96 ([Q32|K32|V32]), K=512, BK=32. A via gload_lds dbuf (8KB);
// B direct from packed PW (coalesced 1KB/fragment, L2-resident). LDS 40KB -> 4 blocks/CU.
__global__ __launch_bounds__(256, 4)
void k_winfuse(const u16* __restrict__ xb, const u16* __restrict__ PW,
               const float* __restrict__ qkv_b, const float* __restrict__ BM2,
               u16* __restrict__ AO) {
  __shared__ u16 lds[20480];   // 40 KiB
  u16* ldsA = lds;             // [2][2048]
  const int tid = threadIdx.x;
  const int lane = tid & 63, wid = tid >> 6;
  const int quad = lane >> 4, col_l = lane & 15;

  // same-window blocks contiguous on one XCD
  const int sb = (blockIdx.x & 7) * 1024 + (blockIdx.x >> 3);
  const int win = sb >> 2, hq = sb & 3;
  const int nimg = win >> 6, a = (win >> 3) & 7, b = win & 7;
  const int head = hq * 4 + wid;

  // A staging: thread -> (row ar, chunk apos); window rows gathered from [nimg][h][w][512]
  const int ar = tid >> 2, apos = tid & 3;
  const int ag = ar >> 3, awl = ar & 7;
  const u16* gA = xb + ((size_t)nimg * 4096 + (a * 8 + ag) * 64 + b * 8 + awl) * 512
                  + (apos ^ ((ar >> 1) & 3)) * 8;

  auto STAGEA = [&](int s) {
    gload16(gA + s * 32, &ldsA[(s & 1) * 2048 + tid * 8]);
  };

  const u16* bpB = PW + (size_t)head * 6 * 8192;  // per-head fragment block

  STAGEA(0);
  f32x4 acc[4][6] = {};   // [m-frag][q0,q1,k0,k1,v0,v1]

#pragma unroll 1
  for (int kt = 0; kt < 16; ++kt) {
    const int ba = (kt & 1) * 2048;
    s16x8 bf[6];
#pragma unroll
    for (int nf = 0; nf < 6; ++nf)
      bf[nf] = *(const s16x8*)&bpB[(size_t)nf * 8192 + kt * 512 + lane * 8];
    if (kt < 15) { STAGEA(kt + 1); WAITVM(7); }   // drains A(kt); bf x6 + A(kt+1) in flight
    else         { WAITVM(6); }                   // drains A(15); bf x6 in flight
    BARRIER();
    s16x8 af[4];
#pragma unroll
    for (int mf = 0; mf < 4; ++mf) {
      const int row = mf * 16 + col_l;
      af[mf] = *(const s16x8*)&ldsA[ba + row * 32 + ((quad ^ ((row >> 1) & 3)) * 8)];
    }
    __builtin_amdgcn_s_setprio(1);
#pragma unroll
    for (int mf = 0; mf < 4; ++mf)
#pragma unroll
      for (int nf = 0; nf < 6; ++nf)
        acc[mf][nf] = mfma16(af[mf], bf[nf], acc[mf][nf]);
    __builtin_amdgcn_s_setprio(0);
    BARRIER();
  }

  // ---- attention tail (r13-validated, per-wave scratch) ----
  u16* sq = &lds[4096 + wid * 4096];  // Q [64][32] swizzled (4KB)
  u16* sk = sq + 2048;                // K [64][32] swizzled (4KB)
  u16* sp = sq;                       // P [64][64] swizzled (8KB, overlays Q+K)

  const float scale = 0.17677669529663687f;  // 1/sqrt(32)
  const float* mrow = BM2 + (((size_t)(a * 8 + b) * 16 + head) << 12);

  const float qb0 = qkv_b[head * 32 + col_l],        qb1 = qkv_b[head * 32 + 16 + col_l];
  const float kb0 = qkv_b[512 + head * 32 + col_l],  kb1 = qkv_b[512 + head * 32 + 16 + col_l];
  const float vb0 = qkv_b[1024 + head * 32 + col_l], vb1 = qkv_b[1024 + head * 32 + 16 + col_l];

  // write Q (scaled+bias), K (bias) to scratch: [e][d], chunk ^= (e>>1)&3
#pragma unroll
  for (int r = 0; r < 4; ++r)
#pragma unroll
    for (int half = 0; half < 2; ++half)
#pragma unroll
      for (int i = 0; i < 4; ++i) {
        const int e = r * 16 + quad * 4 + i;
        const int d = half * 16 + col_l;
        const int sw = (((d >> 3) ^ ((e >> 1) & 3)) << 3) + (d & 7);
        sq[e * 32 + sw] = f2bf((acc[r][half][i] + (half ? qb1 : qb0)) * scale);
        sk[e * 32 + sw] = f2bf(acc[r][2 + half][i] + (half ? kb1 : kb0));
      }

  // S = Q K^T
  float rinv[4][4];
  {
    s16x8 aq[4], bk[4];
    const int ssw = (quad ^ ((col_l >> 1) & 3)) << 3;
#pragma unroll
    for (int t = 0; t < 4; ++t) {
      aq[t] = *(const s16x8*)&sq[(t * 16 + col_l) * 32 + ssw];
      bk[t] = *(const s16x8*)&sk[(t * 16 + col_l) * 32 + ssw];
    }
    f32x4 s[4][4] = {};
#pragma unroll
    for (int r = 0; r < 4; ++r)
#pragma unroll
      for (int c = 0; c < 4; ++c)
        s[r][c] = mfma16(aq[r], bk[c], s[r][c]);

    // fused bias+mask (one coalesced load per element)
#pragma unroll
    for (int r = 0; r < 4; ++r)
#pragma unroll
      for (int c = 0; c < 4; ++c)
#pragma unroll
        for (int i = 0; i < 4; ++i) {
          const int row = r * 16 + quad * 4 + i, col = c * 16 + col_l;
          s[r][c][i] += mrow[row * 64 + col];
        }

    // softmax (deferred 1/sum)
#pragma unroll
    for (int r = 0; r < 4; ++r) {
#pragma unroll
      for (int i = 0; i < 4; ++i) {
        float mx = fmaxf(fmaxf(s[r][0][i], s[r][1][i]), fmaxf(s[r][2][i], s[r][3][i]));
        mx = fmaxf(mx, __shfl_xor(mx, 1));
        mx = fmaxf(mx, __shfl_xor(mx, 2));
        mx = fmaxf(mx, __shfl_xor(mx, 4));
        mx = fmaxf(mx, __shfl_xor(mx, 8));
        float sum = 0.f;
#pragma unroll
        for (int c = 0; c < 4; ++c) {
          float p = __expf(s[r][c][i] - mx);
          s[r][c][i] = p;
          sum += p;
        }
        sum += __shfl_xor(sum, 1);
        sum += __shfl_xor(sum, 2);
        sum += __shfl_xor(sum, 4);
        sum += __shfl_xor(sum, 8);
        rinv[r][i] = 1.0f / sum;
      }
    }

    // P -> scratch (overlays Q+K; both consumed)
#pragma unroll
    for (int r = 0; r < 4; ++r)
#pragma unroll
      for (int c = 0; c < 4; ++c)
#pragma unroll
        for (int i = 0; i < 4; ++i) {
          const int row = r * 16 + quad * 4 + i, col = c * 16 + col_l;
          sp[(row * 64 + col) ^ ((row & 7) << 3)] = f2bf(s[r][c][i]);
        }
  }

  // V: C-frag -> PV B-frag purely in registers (cross-quad shuffle)
  s16x8 bv[2][2];
#pragma unroll
  for (int cf = 0; cf < 2; ++cf) {
    const float vb = cf ? vb1 : vb0;
#pragma unroll
    for (int ks = 0; ks < 2; ++ks) {
      const int rA = ks * 2, rB = ks * 2 + 1;
      u32 A0 = pk2(acc[rA][4 + cf][0] + vb, acc[rA][4 + cf][1] + vb);
      u32 A1 = pk2(acc[rA][4 + cf][2] + vb, acc[rA][4 + cf][3] + vb);
      u32 B0 = pk2(acc[rB][4 + cf][0] + vb, acc[rB][4 + cf][1] + vb);
      u32 B1 = pk2(acc[rB][4 + cf][2] + vb, acc[rB][4 + cf][3] + vb);
      const int l0 = ((quad * 2) & 3) * 16 + col_l;
      const int l1 = ((quad * 2 + 1) & 3) * 16 + col_l;
      u32 a0 = (u32)__shfl((int)A0, l0), a1 = (u32)__shfl((int)A1, l0);
      u32 a2 = (u32)__shfl((int)A0, l1), a3 = (u32)__shfl((int)A1, l1);
      u32 b0 = (u32)__shfl((int)B0, l0), b1 = (u32)__shfl((int)B1, l0);
      u32 b2 = (u32)__shfl((int)B0, l1), b3 = (u32)__shfl((int)B1, l1);
      u32x4 wv;
      if (quad < 2) { wv[0] = a0; wv[1] = a1; wv[2] = a2; wv[3] = a3; }
      else          { wv[0] = b0; wv[1] = b1; wv[2] = b2; wv[3] = b3; }
      bv[cf][ks] = __builtin_bit_cast(s16x8, wv);
    }
  }

  // O = P V
  f32x4 o[4][2] = {};
#pragma unroll
  for (int r = 0; r < 4; ++r) {
#pragma unroll
    for (int ks = 0; ks < 2; ++ks) {
      const int row = r * 16 + col_l;
      s16x8 pa = *(const s16x8*)&sp[(row * 64 + ks * 32 + quad * 8) ^ ((row & 7) << 3)];
#pragma unroll
      for (int cf = 0; cf < 2; ++cf)
        o[r][cf] = mfma16(pa, bv[cf][ks], o[r][cf]);
    }
  }

  // normalize + 4x4 shuffle transpose -> 8B stores to AO [m][512]
#pragma unroll
  for (int r = 0; r < 4; ++r) {
#pragma unroll
    for (int cf = 0; cf < 2; ++cf) {
      float v0 = o[r][cf][0] * rinv[r][0], v1 = o[r][cf][1] * rinv[r][1];
      float v2 = o[r][cf][2] * rinv[r][2], v3 = o[r][cf][3] * rinv[r][3];
      float sA = (lane & 1) ? v0 : v1; sA = __shfl_xor(sA, 1);
      float sB = (lane & 1) ? v2 : v3; sB = __shfl_xor(sB, 1);
      u32 pa_, pb_;
      if (lane & 1) { pa_ = pk2(sA, v1); pb_ = pk2(sB, v3); }
      else          { pa_ = pk2(v0, sA); pb_ = pk2(v2, sB); }
      u32 s2 = (lane & 2) ? pa_ : pb_;
      s2 = (u32)__shfl_xor((int)s2, 2);
      u32x2 val;
      if (lane & 2) { val.x = s2;  val.y = pb_; }
      else          { val.x = pa_; val.y = s2;  }
      const int e = r * 16 + quad * 4 + (col_l & 3);
      const int h = a * 8 + (e >> 3), w = b * 8 + (e & 7);
      const size_t m = (size_t)nimg * 4096 + (size_t)h * 64 + w;
      *(u32x2*)&AO[m * 512 + head * 32 + cf * 16 + (col_l & ~3)] = val;
    }
  }
}

// ---------------- GEMM2: 128x128 tile, BK=32, 4 waves, dbuf, 4 blocks/CU (r12) ----------------
__global__ __launch_bounds__(256, 4)
void k_gemm2(const u16* __restrict__ A, const u16* __restrict__ B,
             const float* __restrict__ bias, float* __restrict__ Out, int ntn) {
  __shared__ u16 lds[16384];        // 32 KiB
  u16* ldsA = lds;                  // [2][4096]
  u16* ldsB = lds + 8192;           // [2][4096]
  const int tid = threadIdx.x;
  const int lane = tid & 63, wid = tid >> 6;
  const int quad = lane >> 4, col_l = lane & 15;
  const int wr = wid >> 1, wc = wid & 1;

  const int cpx = gridDim.x >> 3;
  const int sb = (blockIdx.x & 7) * cpx + (blockIdx.x >> 3);
  const int mt = sb / ntn, nt = sb - mt * ntn;
  const int m0 = mt * 128, n0 = nt * 128;

  const int sr = tid >> 2, sp_ = tid & 3;
  const size_t gA = (size_t)(m0 + sr) * 512 + (sp_ ^ ((sr >> 1) & 3)) * 8;
  const size_t gB = (size_t)(n0 + sr) * 512 + (sp_ ^ ((sr >> 1) & 3)) * 8;

  auto STAGE = [&](int s) {
    const int b = (s & 1) * 4096;
    const int k = s * 32;
    gload16(A + gA + k, &ldsA[b + tid * 8]);
    gload16(A + gA + 64 * 512 + k, &ldsA[b + 2048 + tid * 8]);
    gload16(B + gB + k, &ldsB[b + tid * 8]);
    gload16(B + gB + 64 * 512 + k, &ldsB[b + 2048 + tid * 8]);
  };

  STAGE(0);
  f32x4 acc[4][4] = {};

  for (int kt = 0; kt < 16; ++kt) {
    const int bu = (kt & 1) * 4096;
    if (kt < 15) { STAGE(kt + 1); WAITVM(4); }
    else         { WAITVM(0); }
    BARRIER();
    s16x8 af[4], bf[4];
#pragma unroll
    for (int mf = 0; mf < 4; ++mf) {
      const int row = wr * 64 + mf * 16 + col_l;
      af[mf] = *(const s16x8*)&ldsA[bu + row * 32 + ((quad ^ ((row >> 1) & 3)) * 8)];
    }
#pragma unroll
    for (int nf = 0; nf < 4; ++nf) {
      const int row = wc * 64 + nf * 16 + col_l;
      bf[nf] = *(const s16x8*)&ldsB[bu + row * 32 + ((quad ^ ((row >> 1) & 3)) * 8)];
    }
    __builtin_amdgcn_s_setprio(1);
#pragma unroll
    for (int mf = 0; mf < 4; ++mf)
#pragma unroll
      for (int nf = 0; nf < 4; ++nf)
        acc[mf][nf] = mfma16(af[mf], bf[nf], acc[mf][nf]);
    __builtin_amdgcn_s_setprio(0);
    BARRIER();
  }

  // fp32 epilogue: two 64-row passes through LDS (f32 [64][128] = 32 KB)
#pragma unroll
  for (int p = 0; p < 2; ++p) {
    if (p) __syncthreads();
    if (wr == p) {
#pragma unroll
      for (int c = 0; c < 4; ++c) {
        const float bv = bias[n0 + wc * 64 + c * 16 + col_l];
#pragma unroll
        for (int r = 0; r < 4; ++r) {
          float v0 = acc[r][c][0] + bv, v1 = acc[r][c][1] + bv;
          float v2 = acc[r][c][2] + bv, v3 = acc[r][c][3] + bv;
          float sA = (lane & 1) ? v0 : v1; sA = __shfl_xor(sA, 1);
          float sB = (lane & 1) ? v2 : v3; sB = __shfl_xor(sB, 1);
          float A0, A1, B0, B1;
          if (lane & 1) { A0 = sA; A1 = v1; B0 = sB; B1 = v3; }
          else          { A0 = v0; A1 = sA; B0 = v2; B1 = sB; }
          float t0 = (lane & 2) ? A0 : B0; t0 = __shfl_xor(t0, 2);
          float t1 = (lane & 2) ? A1 : B1; t1 = __shfl_xor(t1, 2);
          f32x4 outv;
          if (lane & 2) { outv[0] = t0; outv[1] = t1; outv[2] = B0; outv[3] = B1; }
          else          { outv[0] = A0; outv[1] = A1; outv[2] = t0; outv[3] = t1; }
          const int lr = r * 16 + quad * 4 + (col_l & 3);
          const int ck = (wc * 64 + c * 16 + (col_l & ~3)) >> 2;
          *(f32x4*)((char*)lds + lr * 512 + ((ck ^ (lr & 7)) << 4)) = outv;
        }
      }
    }
    __syncthreads();
#pragma unroll
    for (int it = 0; it < 8; ++it) {
      const int row = it * 8 + (tid >> 5);
      const int cl = tid & 31;
      f32x4 v = *(const f32x4*)((char*)lds + row * 512 + ((cl ^ (row & 7)) << 4));
      const int m = m0 + p * 64 + row;
      *(f32x4*)&Out[(size_t)m * 512 + n0 + cl * 4] = v;
    }
  }
}

// ---------------- launch ----------------
extern "C" void kernel_launch(void* const* d_in, const int* in_sizes, int n_in,
                              void* d_out, int out_size, void* d_ws, size_t ws_size,
                              hipStream_t stream) {
  const float* x     = (const float*)d_in[0];
  const float* mask  = (const float*)d_in[1];
  const float* qkv_w = (const float*)d_in[2];
  const float* qkv_b = (const float*)d_in[3];
  const float* out_w = (const float*)d_in[4];
  const float* out_b = (const float*)d_in[5];
  const float* btab  = (const float*)d_in[6];

  char* ws = (char*)d_ws;
  u16* xb    = (u16*)ws;                        // 134,217,728 B (x bf16)
  u16* ao    = (u16*)(ws + 134217728);          // 134,217,728 B (attn out bf16)
  u16* pw    = (u16*)(ws + 268435456);          // 1,572,864 B (packed qkv_w)
  u16* woT   = (u16*)(ws + 270008320);          // 524,288 B

  // BM2 (64 MB f32) parked in d_out; dead once k_winfuse finishes, overwritten by GEMM2.
  float* bm2 = (float*)d_out;

  k_conv_x<<<32768, 256, 0, stream>>>(x, xb, 8388608);
  k_pack_wqkv<<<384, 256, 0, stream>>>(qkv_w, pw);
  k_transpose_w<<<1024, 256, 0, stream>>>(out_w, woT, 512, 512);
  k_prep_bm<<<16384, 256, 0, stream>>>(mask, btab, bm2);
  k_winfuse<<<8192, 256, 0, stream>>>(xb, pw, qkv_b, bm2, ao);
  k_gemm2<<<4096, 256, 0, stream>>>(ao, woT, out_b, (float*)d_out, 4);
}

// Round 16
// 530.239 us; speedup vs baseline: 2.8331x; 2.8331x over previous
//
#include <hip/hip_runtime.h>
#include <hip/hip_bf16.h>
#include <stdint.h>

// Swin windowed MHA: N=32, H=W=64, C=512, heads=16, head_dim=32, window 8x8 (E=64).
// conv x->bf16 ; pack qkv_w (fragment order) ; transpose out_w ; prep BM2 = bias+mask
// fused table (parked in d_out) ; k_winfuse (fused QKV-proj + windowed attn, (256,3)) ;
// GEMM2 (r12 structure, fp32 out).

typedef __attribute__((ext_vector_type(4))) float  f32x4;
typedef __attribute__((ext_vector_type(4))) float  fvec4;
typedef __attribute__((ext_vector_type(8))) short  s16x8;
typedef __attribute__((ext_vector_type(8))) __bf16 bf16x8;
typedef __attribute__((ext_vector_type(2))) unsigned int u32x2;
typedef __attribute__((ext_vector_type(4))) unsigned int u32x4;
typedef unsigned short u16;
typedef unsigned int   u32;
typedef __attribute__((ext_vector_type(4))) u16 u16x4;
typedef __attribute__((ext_vector_type(8))) u16 u16x8;

__device__ __forceinline__ u16 f2bf(float f) {
  u32 u = __builtin_bit_cast(u32, f);
  u32 r = (u + 0x7FFFu + ((u >> 16) & 1u)) >> 16;
  return (u16)r;
}
__device__ __forceinline__ u32 pk2(float x, float y) {
  return (u32)f2bf(x) | ((u32)f2bf(y) << 16);
}

__device__ __forceinline__ f32x4 mfma16(s16x8 a, s16x8 b, f32x4 c) {
  return __builtin_amdgcn_mfma_f32_16x16x32_bf16((bf16x8)a, (bf16x8)b, c, 0, 0, 0);
}

__device__ __forceinline__ void gload16(const u16* g, u16* l) {
  __builtin_amdgcn_global_load_lds(
      (const __attribute__((address_space(1))) u32*)g,
      (__attribute__((address_space(3))) u32*)l, 16, 0, 0);
}

#define BARRIER() asm volatile("s_barrier" ::: "memory")
#define WAITVM(n) asm volatile("s_waitcnt vmcnt(" #n ")" ::: "memory")

// ---------------- conversion / packing kernels ----------------
__global__ void k_conv_x(const float* __restrict__ x, u16* __restrict__ xb, int n8) {
  int i = blockIdx.x * 256 + threadIdx.x;
  if (i >= n8) return;
  fvec4 v0 = ((const fvec4*)x)[i * 2];
  fvec4 v1 = ((const fvec4*)x)[i * 2 + 1];
  u16x8 o;
  o[0] = f2bf(v0.x); o[1] = f2bf(v0.y); o[2] = f2bf(v0.z); o[3] = f2bf(v0.w);
  o[4] = f2bf(v1.x); o[5] = f2bf(v1.y); o[6] = f2bf(v1.z); o[7] = f2bf(v1.w);
  ((u16x8*)xb)[i] = o;
}

__global__ void k_transpose_w(const float* __restrict__ w, u16* __restrict__ wt, int K, int N) {
  int i = blockIdx.x * 256 + threadIdx.x;
  if (i >= K * N) return;
  int k = i / N, n = i - k * N;
  wt[n * K + k] = f2bf(w[i]);
}

// pack qkv_w [512][1536] f32 -> PW bf16 fragment order (r6-validated)
__global__ void k_pack_wqkv(const float* __restrict__ w, u16* __restrict__ pw) {
  int id = blockIdx.x * 256 + threadIdx.x;
  const int lane = id & 63;
  int r = id >> 6;
  const int kt = r & 15; r >>= 4;
  const int nf = r & 1;  r >>= 1;
  const int s = r % 3;
  const int H = r / 3;
  const int n = s * 512 + H * 32 + nf * 16 + (lane & 15);
  const int k0 = kt * 32 + (lane >> 4) * 8;
  u16 tmp[8];
#pragma unroll
  for (int j = 0; j < 8; ++j) tmp[j] = f2bf(w[(size_t)(k0 + j) * 1536 + n]);
  *(s16x8*)&pw[(size_t)id * 8] = *(const s16x8*)tmp;
}

// BM2[wh][ww][head][row][col] = rel_bias[head][row][col] + mask[wh][ww][row][col]
__global__ void k_prep_bm(const float* __restrict__ mask, const float* __restrict__ btab,
                          float* __restrict__ bm2) {
  int id = blockIdx.x * 256 + threadIdx.x;   // 4,194,304 total
  const int col = id & 63;
  const int row = (id >> 6) & 63;
  const int head = (id >> 12) & 15;
  const int wb = id >> 16;                   // wh*8+ww
  const int dh = (row >> 3) - (col >> 3) + 7;
  const int dw = (row & 7) - (col & 7) + 7;
  bm2[id] = btab[(dh * 15 + dw) * 16 + head] + mask[(size_t)(wb * 64 + row) * 64 + col];
}

// ---------------- fused QKV-proj + windowed attention ----------------
// Block = (window, head-quad): 8192 blocks, 256 thr = 4 waves, wave wid owns head hq*4+wid.
// Proj: M=64, per-wave N=96 ([Q32|K32|V32]), K=512, BK=32. A via gload_lds dbuf (8KB);
// B direct from packed PW (coalesced 1KB/fragment, L2-resident). LDS 40KB.
// launch_bounds (256,3): 84 VGPR in r14 -- (256,4) forces 64 VGPR and spills (r15).
__global__ __launch_bounds__(256, 3)
void k_winfuse(const u16* __restrict__ xb, const u16* __restrict__ PW,
               const float* __restrict__ qkv_b, const float* __restrict__ BM2,
               u16* __restrict__ AO) {
  __shared__ u16 lds[20480];   // 40 KiB
  u16* ldsA = lds;             // [2][2048]
  const int tid = threadIdx.x;
  const int lane = tid & 63, wid = tid >> 6;
  const int quad = lane >> 4, col_l = lane & 15;

  // same-window blocks contiguous on one XCD
  const int sb = (blockIdx.x & 7) * 1024 + (blockIdx.x >> 3);
  const int win = sb >> 2, hq = sb & 3;
  const int nimg = win >> 6, a = (win >> 3) & 7, b = win & 7;
  const int head = hq * 4 + wid;

  // A staging: thread -> (row ar, chunk apos); window rows gathered from [nimg][h][w][512]
  const int ar = tid >> 2, apos = tid & 3;
  const int ag = ar >> 3, awl = ar & 7;
  const u16* gA = xb + ((size_t)nimg * 4096 + (a * 8 + ag) * 64 + b * 8 + awl) * 512
                  + (apos ^ ((ar >> 1) & 3)) * 8;

  auto STAGEA = [&](int s) {
    gload16(gA + s * 32, &ldsA[(s & 1) * 2048 + tid * 8]);
  };

  const u16* bpB = PW + (size_t)head * 6 * 8192;  // per-head fragment block

  STAGEA(0);
  f32x4 acc[4][6] = {};   // [m-frag][q0,q1,k0,k1,v0,v1]

#pragma unroll 1
  for (int kt = 0; kt < 16; ++kt) {
    const int ba = (kt & 1) * 2048;
    s16x8 bf[6];
#pragma unroll
    for (int nf = 0; nf < 6; ++nf)
      bf[nf] = *(const s16x8*)&bpB[(size_t)nf * 8192 + kt * 512 + lane * 8];
    if (kt < 15) { STAGEA(kt + 1); WAITVM(7); }   // drains A(kt); bf x6 + A(kt+1) in flight
    else         { WAITVM(6); }                   // drains A(15); bf x6 in flight
    BARRIER();
    s16x8 af[4];
#pragma unroll
    for (int mf = 0; mf < 4; ++mf) {
      const int row = mf * 16 + col_l;
      af[mf] = *(const s16x8*)&ldsA[ba + row * 32 + ((quad ^ ((row >> 1) & 3)) * 8)];
    }
    __builtin_amdgcn_s_setprio(1);
#pragma unroll
    for (int mf = 0; mf < 4; ++mf)
#pragma unroll
      for (int nf = 0; nf < 6; ++nf)
        acc[mf][nf] = mfma16(af[mf], bf[nf], acc[mf][nf]);
    __builtin_amdgcn_s_setprio(0);
    BARRIER();
  }

  // ---- attention tail (r13-validated, per-wave scratch) ----
  u16* sq = &lds[4096 + wid * 4096];  // Q [64][32] swizzled (4KB)
  u16* sk = sq + 2048;                // K [64][32] swizzled (4KB)
  u16* sp = sq;                       // P [64][64] swizzled (8KB, overlays Q+K)

  const float scale = 0.17677669529663687f;  // 1/sqrt(32)
  const float* mrow = BM2 + (((size_t)(a * 8 + b) * 16 + head) << 12);

  const float qb0 = qkv_b[head * 32 + col_l],        qb1 = qkv_b[head * 32 + 16 + col_l];
  const float kb0 = qkv_b[512 + head * 32 + col_l],  kb1 = qkv_b[512 + head * 32 + 16 + col_l];
  const float vb0 = qkv_b[1024 + head * 32 + col_l], vb1 = qkv_b[1024 + head * 32 + 16 + col_l];

  // write Q (scaled+bias), K (bias) to scratch: [e][d], chunk ^= (e>>1)&3
#pragma unroll
  for (int r = 0; r < 4; ++r)
#pragma unroll
    for (int half = 0; half < 2; ++half)
#pragma unroll
      for (int i = 0; i < 4; ++i) {
        const int e = r * 16 + quad * 4 + i;
        const int d = half * 16 + col_l;
        const int sw = (((d >> 3) ^ ((e >> 1) & 3)) << 3) + (d & 7);
        sq[e * 32 + sw] = f2bf((acc[r][half][i] + (half ? qb1 : qb0)) * scale);
        sk[e * 32 + sw] = f2bf(acc[r][2 + half][i] + (half ? kb1 : kb0));
      }

  // S = Q K^T
  float rinv[4][4];
  {
    s16x8 aq[4], bk[4];
    const int ssw = (quad ^ ((col_l >> 1) & 3)) << 3;
#pragma unroll
    for (int t = 0; t < 4; ++t) {
      aq[t] = *(const s16x8*)&sq[(t * 16 + col_l) * 32 + ssw];
      bk[t] = *(const s16x8*)&sk[(t * 16 + col_l) * 32 + ssw];
    }
    f32x4 s[4][4] = {};
#pragma unroll
    for (int r = 0; r < 4; ++r)
#pragma unroll
      for (int c = 0; c < 4; ++c)
        s[r][c] = mfma16(aq[r], bk[c], s[r][c]);

    // fused bias+mask (one coalesced load per element)
#pragma unroll
    for (int r = 0; r < 4; ++r)
#pragma unroll
      for (int c = 0; c < 4; ++c)
#pragma unroll
        for (int i = 0; i < 4; ++i) {
          const int row = r * 16 + quad * 4 + i, col = c * 16 + col_l;
          s[r][c][i] += mrow[row * 64 + col];
        }

    // softmax (deferred 1/sum)
#pragma unroll
    for (int r = 0; r < 4; ++r) {
#pragma unroll
      for (int i = 0; i < 4; ++i) {
        float mx = fmaxf(fmaxf(s[r][0][i], s[r][1][i]), fmaxf(s[r][2][i], s[r][3][i]));
        mx = fmaxf(mx, __shfl_xor(mx, 1));
        mx = fmaxf(mx, __shfl_xor(mx, 2));
        mx = fmaxf(mx, __shfl_xor(mx, 4));
        mx = fmaxf(mx, __shfl_xor(mx, 8));
        float sum = 0.f;
#pragma unroll
        for (int c = 0; c < 4; ++c) {
          float p = __expf(s[r][c][i] - mx);
          s[r][c][i] = p;
          sum += p;
        }
        sum += __shfl_xor(sum, 1);
        sum += __shfl_xor(sum, 2);
        sum += __shfl_xor(sum, 4);
        sum += __shfl_xor(sum, 8);
        rinv[r][i] = 1.0f / sum;
      }
    }

    // P -> scratch (overlays Q+K; both consumed)
#pragma unroll
    for (int r = 0; r < 4; ++r)
#pragma unroll
      for (int c = 0; c < 4; ++c)
#pragma unroll
        for (int i = 0; i < 4; ++i) {
          const int row = r * 16 + quad * 4 + i, col = c * 16 + col_l;
          sp[(row * 64 + col) ^ ((row & 7) << 3)] = f2bf(s[r][c][i]);
        }
  }

  // V: C-frag -> PV B-frag purely in registers (cross-quad shuffle)
  s16x8 bv[2][2];
#pragma unroll
  for (int cf = 0; cf < 2; ++cf) {
    const float vb = cf ? vb1 : vb0;
#pragma unroll
    for (int ks = 0; ks < 2; ++ks) {
      const int rA = ks * 2, rB = ks * 2 + 1;
      u32 A0 = pk2(acc[rA][4 + cf][0] + vb, acc[rA][4 + cf][1] + vb);
      u32 A1 = pk2(acc[rA][4 + cf][2] + vb, acc[rA][4 + cf][3] + vb);
      u32 B0 = pk2(acc[rB][4 + cf][0] + vb, acc[rB][4 + cf][1] + vb);
      u32 B1 = pk2(acc[rB][4 + cf][2] + vb, acc[rB][4 + cf][3] + vb);
      const int l0 = ((quad * 2) & 3) * 16 + col_l;
      const int l1 = ((quad * 2 + 1) & 3) * 16 + col_l;
      u32 a0 = (u32)__shfl((int)A0, l0), a1 = (u32)__shfl((int)A1, l0);
      u32 a2 = (u32)__shfl((int)A0, l1), a3 = (u32)__shfl((int)A1, l1);
      u32 b0 = (u32)__shfl((int)B0, l0), b1 = (u32)__shfl((int)B1, l0);
      u32 b2 = (u32)__shfl((int)B0, l1), b3 = (u32)__shfl((int)B1, l1);
      u32x4 wv;
      if (quad < 2) { wv[0] = a0; wv[1] = a1; wv[2] = a2; wv[3] = a3; }
      else          { wv[0] = b0; wv[1] = b1; wv[2] = b2; wv[3] = b3; }
      bv[cf][ks] = __builtin_bit_cast(s16x8, wv);
    }
  }

  // O = P V
  f32x4 o[4][2] = {};
#pragma unroll
  for (int r = 0; r < 4; ++r) {
#pragma unroll
    for (int ks = 0; ks < 2; ++ks) {
      const int row = r * 16 + col_l;
      s16x8 pa = *(const s16x8*)&sp[(row * 64 + ks * 32 + quad * 8) ^ ((row & 7) << 3)];
#pragma unroll
      for (int cf = 0; cf < 2; ++cf)
        o[r][cf] = mfma16(pa, bv[cf][ks], o[r][cf]);
    }
  }

  // normalize + 4x4 shuffle transpose -> 8B stores to AO [m][512]
#pragma unroll
  for (int r = 0; r < 4; ++r) {
#pragma unroll
    for (int cf = 0; cf < 2; ++cf) {
      float v0 = o[r][cf][0] * rinv[r][0], v1 = o[r][cf][1] * rinv[r][1];
      float v2 = o[r][cf][2] * rinv[r][2], v3 = o[r][cf][3] * rinv[r][3];
      float sA = (lane & 1) ? v0 : v1; sA = __shfl_xor(sA, 1);
      float sB = (lane & 1) ? v2 : v3; sB = __shfl_xor(sB, 1);
      u32 pa_, pb_;
      if (lane & 1) { pa_ = pk2(sA, v1); pb_ = pk2(sB, v3); }
      else          { pa_ = pk2(v0, sA); pb_ = pk2(v2, sB); }
      u32 s2 = (lane & 2) ? pa_ : pb_;
      s2 = (u32)__shfl_xor((int)s2, 2);
      u32x2 val;
      if (lane & 2) { val.x = s2;  val.y = pb_; }
      else          { val.x = pa_; val.y = s2;  }
      const int e = r * 16 + quad * 4 + (col_l & 3);
      const int h = a * 8 + (e >> 3), w = b * 8 + (e & 7);
      const size_t m = (size_t)nimg * 4096 + (size_t)h * 64 + w;
      *(u32x2*)&AO[m * 512 + head * 32 + cf * 16 + (col_l & ~3)] = val;
    }
  }
}

// ---------------- GEMM2: 128x128 tile, BK=32, 4 waves, dbuf, 4 blocks/CU (r12) ----------------
__global__ __launch_bounds__(256, 4)
void k_gemm2(const u16* __restrict__ A, const u16* __restrict__ B,
             const float* __restrict__ bias, float* __restrict__ Out, int ntn) {
  __shared__ u16 lds[16384];        // 32 KiB
  u16* ldsA = lds;                  // [2][4096]
  u16* ldsB = lds + 8192;           // [2][4096]
  const int tid = threadIdx.x;
  const int lane = tid & 63, wid = tid >> 6;
  const int quad = lane >> 4, col_l = lane & 15;
  const int wr = wid >> 1, wc = wid & 1;

  const int cpx = gridDim.x >> 3;
  const int sb = (blockIdx.x & 7) * cpx + (blockIdx.x >> 3);
  const int mt = sb / ntn, nt = sb - mt * ntn;
  const int m0 = mt * 128, n0 = nt * 128;

  const int sr = tid >> 2, sp_ = tid & 3;
  const size_t gA = (size_t)(m0 + sr) * 512 + (sp_ ^ ((sr >> 1) & 3)) * 8;
  const size_t gB = (size_t)(n0 + sr) * 512 + (sp_ ^ ((sr >> 1) & 3)) * 8;

  auto STAGE = [&](int s) {
    const int b = (s & 1) * 4096;
    const int k = s * 32;
    gload16(A + gA + k, &ldsA[b + tid * 8]);
    gload16(A + gA + 64 * 512 + k, &ldsA[b + 2048 + tid * 8]);
    gload16(B + gB + k, &ldsB[b + tid * 8]);
    gload16(B + gB + 64 * 512 + k, &ldsB[b + 2048 + tid * 8]);
  };

  STAGE(0);
  f32x4 acc[4][4] = {};

  for (int kt = 0; kt < 16; ++kt) {
    const int bu = (kt & 1) * 4096;
    if (kt < 15) { STAGE(kt + 1); WAITVM(4); }
    else         { WAITVM(0); }
    BARRIER();
    s16x8 af[4], bf[4];
#pragma unroll
    for (int mf = 0; mf < 4; ++mf) {
      const int row = wr * 64 + mf * 16 + col_l;
      af[mf] = *(const s16x8*)&ldsA[bu + row * 32 + ((quad ^ ((row >> 1) & 3)) * 8)];
    }
#pragma unroll
    for (int nf = 0; nf < 4; ++nf) {
      const int row = wc * 64 + nf * 16 + col_l;
      bf[nf] = *(const s16x8*)&ldsB[bu + row * 32 + ((quad ^ ((row >> 1) & 3)) * 8)];
    }
    __builtin_amdgcn_s_setprio(1);
#pragma unroll
    for (int mf = 0; mf < 4; ++mf)
#pragma unroll
      for (int nf = 0; nf < 4; ++nf)
        acc[mf][nf] = mfma16(af[mf], bf[nf], acc[mf][nf]);
    __builtin_amdgcn_s_setprio(0);
    BARRIER();
  }

  // fp32 epilogue: two 64-row passes through LDS (f32 [64][128] = 32 KB)
#pragma unroll
  for (int p = 0; p < 2; ++p) {
    if (p) __syncthreads();
    if (wr == p) {
#pragma unroll
      for (int c = 0; c < 4; ++c) {
        const float bv = bias[n0 + wc * 64 + c * 16 + col_l];
#pragma unroll
        for (int r = 0; r < 4; ++r) {
          float v0 = acc[r][c][0] + bv, v1 = acc[r][c][1] + bv;
          float v2 = acc[r][c][2] + bv, v3 = acc[r][c][3] + bv;
          float sA = (lane & 1) ? v0 : v1; sA = __shfl_xor(sA, 1);
          float sB = (lane & 1) ? v2 : v3; sB = __shfl_xor(sB, 1);
          float A0, A1, B0, B1;
          if (lane & 1) { A0 = sA; A1 = v1; B0 = sB; B1 = v3; }
          else          { A0 = v0; A1 = sA; B0 = v2; B1 = sB; }
          float t0 = (lane & 2) ? A0 : B0; t0 = __shfl_xor(t0, 2);
          float t1 = (lane & 2) ? A1 : B1; t1 = __shfl_xor(t1, 2);
          f32x4 outv;
          if (lane & 2) { outv[0] = t0; outv[1] = t1; outv[2] = B0; outv[3] = B1; }
          else          { outv[0] = A0; outv[1] = A1; outv[2] = t0; outv[3] = t1; }
          const int lr = r * 16 + quad * 4 + (col_l & 3);
          const int ck = (wc * 64 + c * 16 + (col_l & ~3)) >> 2;
          *(f32x4*)((char*)lds + lr * 512 + ((ck ^ (lr & 7)) << 4)) = outv;
        }
      }
    }
    __syncthreads();
#pragma unroll
    for (int it = 0; it < 8; ++it) {
      const int row = it * 8 + (tid >> 5);
      const int cl = tid & 31;
      f32x4 v = *(const f32x4*)((char*)lds + row * 512 + ((cl ^ (row & 7)) << 4));
      const int m = m0 + p * 64 + row;
      *(f32x4*)&Out[(size_t)m * 512 + n0 + cl * 4] = v;
    }
  }
}

// ---------------- launch ----------------
extern "C" void kernel_launch(void* const* d_in, const int* in_sizes, int n_in,
                              void* d_out, int out_size, void* d_ws, size_t ws_size,
                              hipStream_t stream) {
  const float* x     = (const float*)d_in[0];
  const float* mask  = (const float*)d_in[1];
  const float* qkv_w = (const float*)d_in[2];
  const float* qkv_b = (const float*)d_in[3];
  const float* out_w = (const float*)d_in[4];
  const float* out_b = (const float*)d_in[5];
  const float* btab  = (const float*)d_in[6];

  char* ws = (char*)d_ws;
  u16* xb    = (u16*)ws;                        // 134,217,728 B (x bf16)
  u16* ao    = (u16*)(ws + 134217728);          // 134,217,728 B (attn out bf16)
  u16* pw    = (u16*)(ws + 268435456);          // 1,572,864 B (packed qkv_w)
  u16* woT   = (u16*)(ws + 270008320);          // 524,288 B

  // BM2 (16 MB f32) parked in d_out; dead once k_winfuse finishes, overwritten by GEMM2.
  float* bm2 = (float*)d_out;

  k_conv_x<<<32768, 256, 0, stream>>>(x, xb, 8388608);
  k_pack_wqkv<<<384, 256, 0, stream>>>(qkv_w, pw);
  k_transpose_w<<<1024, 256, 0, stream>>>(out_w, woT, 512, 512);
  k_prep_bm<<<16384, 256, 0, stream>>>(mask, btab, bm2);
  k_winfuse<<<8192, 256, 0, stream>>>(xb, pw, qkv_b, bm2, ao);
  k_gemm2<<<4096, 256, 0, stream>>>(ao, woT, out_b, (float*)d_out, 4);
}